// Round 1
// baseline (79.447 us; speedup 1.0000x reference)
//
#include <hip/hip_runtime.h>

// BallQLoss: ball_query(pc, r=0.2, k=16) against itself + L1 grouping loss.
// pc: (4, 4096, 3) f32, mask: (4, 4096, 30) f32 -> scalar f32.
//
// R6: pair-per-wave + SoA + dual-row gather.
//  - Q=2 queries per wave: each chunk's LDS candidate load + loop overhead is
//    amortized over two distance tests / ballots. Slot space: lane s holds
//    slot s of q0, lane 16+s holds slot s of q1 (exactly 32 lanes of state).
//  - LDS is SoA (x|y|z planes): candidate address is base+lane, three
//    ds_read_b32 with immediate plane offsets; stride-1 => conflict-free.
//    Staging writes are stride-1 too (conflict-free), 12 B/lane global reads.
//  - Phase-2 gather loads TWO mask rows per instruction: lanes 0-29 read
//    slot-s row of q0, lanes 32-61 slot-s row of q1 => 16 dual loads + 32
//    VALU per PAIR (was 16 loads + 32 VALU per query at 47% lane use).
//  - 8 waves/block (512 thr), 1 pair/wave, 1024 blocks => dynamic balancing
//    of corner queries that scan all 64 chunks.

#define BQ_B 4
#define BQ_N 4096
#define BQ_C 30
#define BQ_K 16
#define BQ_R2 0.04f
#define WAVES_PER_BLOCK 8
#define BLOCK_T (WAVES_PER_BLOCK * 64)                     // 512
#define PAIRS_PER_BLOCK WAVES_PER_BLOCK                    // 1 pair per wave
#define BLOCKS_PER_BATCH (BQ_N / (2 * PAIRS_PER_BLOCK))    // 256
#define GRID (BQ_B * BLOCKS_PER_BATCH)                     // 1024

__global__ __launch_bounds__(BLOCK_T, 4) void ballq_scan_kernel(
    const float* __restrict__ pc,    // (B, N, 3)
    const float* __restrict__ mask,  // (B, N, C)
    float* __restrict__ partial)     // (GRID,) unscaled per-block sums
{
    __shared__ __align__(16) float s[3 * BQ_N];  // SoA planes x|y|z, 48 KB
    __shared__ float wsum[WAVES_PER_BLOCK];

    const int tid  = threadIdx.x;
    const int lane = tid & 63;
    const int wave = tid >> 6;
    const int b        = blockIdx.x / BLOCKS_PER_BATCH;
    const int blk_in_b = blockIdx.x % BLOCKS_PER_BATCH;

    const float* pcb   = pc   + (size_t)b * BQ_N * 3;
    const float* maskb = mask + (size_t)b * BQ_N * BQ_C;

    // SoA stage: thread t handles points t, t+512, ..., t+3584.
    // Global: 3 dword loads/point (wave reads 768 contiguous bytes per plane
    // step). LDS: stride-1 writes per plane => conflict-free.
    #pragma unroll
    for (int k = 0; k < BQ_N / BLOCK_T; ++k) {
        const int p = tid + k * BLOCK_T;
        s[p]             = pcb[3 * p + 0];
        s[p + BQ_N]      = pcb[3 * p + 1];
        s[p + 2 * BQ_N]  = pcb[3 * p + 2];
    }
    __syncthreads();

    // Wave -> query pair (consecutive indices; spatially independent).
    const int gw = blk_in_b * WAVES_PER_BLOCK + wave;
    const int n0 = 2 * gw;
    const int n1 = 2 * gw + 1;

    const float qx0 = s[n0], qy0 = s[n0 + BQ_N], qz0 = s[n0 + 2 * BQ_N];
    const float qx1 = s[n1], qy1 = s[n1 + BQ_N], qz1 = s[n1 + 2 * BQ_N];

    // ---- Phase 1: peel first <=16 in-ball indices for BOTH queries ----
    int f0 = 0, f1 = 0;
    int first0 = 0, first1 = 0;   // self always in-ball => f >= 1
    int sel = 0;                  // lane s: slot s of q0; lane 16+s: slot s of q1

    float cx = s[lane], cy = s[lane + BQ_N], cz = s[lane + 2 * BQ_N];

    for (int base = 0; base < BQ_N; base += 64) {
        // 1-deep LDS prefetch of the next chunk (SoA: one addr, imm offsets).
        const int nb = (base + 64 < BQ_N) ? base + 64 : 0;
        const float nx = s[nb + lane];
        const float ny = s[nb + lane + BQ_N];
        const float nz = s[nb + lane + 2 * BQ_N];

        const float dx0 = cx - qx0, dy0 = cy - qy0, dz0 = cz - qz0;
        const float dx1 = cx - qx1, dy1 = cy - qy1, dz1 = cz - qz1;
        const float d20 = dx0 * dx0 + dy0 * dy0 + dz0 * dz0;
        const float d21 = dx1 * dx1 + dy1 * dy1 + dz1 * dz1;
        unsigned long long b0 = __ballot(d20 < BQ_R2);
        unsigned long long b1 = __ballot(d21 < BQ_R2);

        while (b0 && f0 < BQ_K) {            // wave-uniform scalar loop
            const int bit = __builtin_ctzll(b0);
            b0 &= b0 - 1;
            const int idx = base + bit;
            if (f0 == 0) first0 = idx;
            if (lane == f0) sel = idx;
            ++f0;
        }
        while (b1 && f1 < BQ_K) {
            const int bit = __builtin_ctzll(b1);
            b1 &= b1 - 1;
            const int idx = base + bit;
            if (f1 == 0) first1 = idx;
            if (lane == BQ_K + f1) sel = idx;
            ++f1;
        }
        if (f0 >= BQ_K && f1 >= BQ_K) break;
        cx = nx; cy = ny; cz = nz;
    }
    // Pad remaining slots with first found index (reference semantics).
    if (lane < BQ_K && lane >= f0) sel = first0;
    if (lane >= BQ_K && lane < 2 * BQ_K && (lane - BQ_K) >= f1) sel = first1;

    // ---- Phase 2: dual-row batched gather ----
    // Lane l < 32: channel c=l of q0's rows; lane l >= 32: channel c=l-32 of
    // q1's rows. One load instruction fetches a row for each query.
    const int  c  = lane & 31;
    const bool cv = (c < BQ_C);
    const int  nq = (lane < 32) ? n0 : n1;
    const float qv = cv ? maskb[(size_t)nq * BQ_C + c] : 0.f;

    float vals[BQ_K];
    #pragma unroll
    for (int sdx = 0; sdx < BQ_K; ++sdx) {
        const int nb0 = __shfl(sel, sdx, 64);          // v_readlane -> SGPR
        const int nb1 = __shfl(sel, BQ_K + sdx, 64);
        const int ns  = (lane < 32) ? nb0 : nb1;
        vals[sdx] = cv ? maskb[(size_t)ns * BQ_C + c] : 0.f;
    }
    float acc = 0.f;
    #pragma unroll
    for (int sdx = 0; sdx < BQ_K; ++sdx)
        acc += fabsf(qv - vals[sdx]);

    // Wave reduction (64 lanes): sums q0 channels (lanes 0-29) and q1
    // channels (lanes 32-61) of all 16 slots in one go.
    for (int off = 32; off > 0; off >>= 1)
        acc += __shfl_xor(acc, off, 64);

    if (lane == 0) wsum[wave] = acc;
    __syncthreads();
    if (tid == 0) {
        float t = 0.f;
        #pragma unroll
        for (int w = 0; w < WAVES_PER_BLOCK; ++w) t += wsum[w];
        partial[blockIdx.x] = t;   // non-atomic per-block partial
    }
}

__global__ __launch_bounds__(256) void ballq_finish_kernel(
    const float* __restrict__ partial, float* __restrict__ out)
{
    float t = 0.f;
    for (int i = threadIdx.x; i < GRID; i += 256) t += partial[i];
    for (int off = 32; off > 0; off >>= 1)
        t += __shfl_xor(t, off, 64);
    __shared__ float ws[4];
    if ((threadIdx.x & 63) == 0) ws[threadIdx.x >> 6] = t;
    __syncthreads();
    if (threadIdx.x == 0)
        out[0] = (ws[0] + ws[1] + ws[2] + ws[3]) *
                 (1.0f / ((float)BQ_B * BQ_N * BQ_K));
}

extern "C" void kernel_launch(void* const* d_in, const int* in_sizes, int n_in,
                              void* d_out, int out_size, void* d_ws, size_t ws_size,
                              hipStream_t stream) {
    const float* pc   = (const float*)d_in[0];  // (4, 4096, 3)
    const float* mask = (const float*)d_in[1];  // (4, 4096, 30)
    float* out     = (float*)d_out;
    float* partial = (float*)d_ws;              // GRID floats = 4 KB scratch

    ballq_scan_kernel<<<GRID, BLOCK_T, 0, stream>>>(pc, mask, partial);
    ballq_finish_kernel<<<1, 256, 0, stream>>>(partial, out);
}